// Round 8
// baseline (292.416 us; speedup 1.0000x reference)
//
#include <hip/hip_runtime.h>
#include <hip/hip_bf16.h>

// Problem constants (fixed by the reference)
#define B_   32
#define D_   3584
#define NH_  28
#define NKV_ 4
#define HD_  128
#define SW_  4096
#define GRP_ 7                    // NH/NKV
#define NQKV_ 4608                // (NH+2*NKV)*HD
#define SCALE_ 0.08838834764831845f  // HD^-0.5
#define NKC_ 16                   // split-K chunks for projections
#define KC_  224                  // D_/NKC_
#define NCHUNK_ 16                // attention s-chunks (grid = 32*4*16 = 2048 blocks)
#define CHUNK_ 256                // rows per block
#define TROWS_ 64                 // rows per inner tile
#define NT_ 4                     // CHUNK_/TROWS_

// ---------------------------------------------------------------------------
// Half-wave (32-lane) all-reduce sum, VALU-DPP for 4 of 5 steps (verified R7).
// ---------------------------------------------------------------------------
__device__ __forceinline__ float halfwave_allreduce(float x) {
    x += __int_as_float(__builtin_amdgcn_mov_dpp(__float_as_int(x), 0xB1, 0xF, 0xF, true));
    x += __int_as_float(__builtin_amdgcn_mov_dpp(__float_as_int(x), 0x4E, 0xF, 0xF, true));
    x += __int_as_float(__builtin_amdgcn_mov_dpp(__float_as_int(x), 0x141, 0xF, 0xF, true));
    x += __int_as_float(__builtin_amdgcn_mov_dpp(__float_as_int(x), 0x140, 0xF, 0xF, true));
    x += __int_as_float(__builtin_amdgcn_ds_swizzle(__float_as_int(x), 0x401F));
    return x;
}

// async global->LDS DMA, 16B per lane. ldst wave-uniform, gsrc per-lane.
__device__ __forceinline__ void dma16(const float* gsrc, float* ldst) {
    __builtin_amdgcn_global_load_lds(
        (const __attribute__((address_space(1))) unsigned int*)gsrc,
        (__attribute__((address_space(3))) unsigned int*)ldst, 16, 0, 0);
}

// ---------------------------------------------------------------------------
// Split-K projection: P[kc][32][N] = X[32][3584] @ W[3584][N]  (partial sums)
// ---------------------------------------------------------------------------
__global__ __launch_bounds__(256) void proj_kernel(const float* __restrict__ X,
                                                   const float* __restrict__ W,
                                                   float* __restrict__ P, int N) {
    const int lane = threadIdx.x & 63;
    const int wv   = __builtin_amdgcn_readfirstlane(threadIdx.x >> 6);
    const int r0   = wv * 8;
    const int c2   = blockIdx.x * 64 + lane;   // float2 column index
    const int k0   = blockIdx.y * KC_;
    const int n2   = N >> 1;
    const float2* __restrict__ W2 = (const float2*)W;

    float2 acc[8];
#pragma unroll
    for (int i = 0; i < 8; ++i) acc[i] = make_float2(0.f, 0.f);

#pragma unroll 8
    for (int k = k0; k < k0 + KC_; ++k) {
        float2 w2 = W2[(size_t)k * n2 + c2];
#pragma unroll
        for (int i = 0; i < 8; ++i) {
            float xr = X[(size_t)(r0 + i) * D_ + k];   // wave-uniform -> s_load
            acc[i].x += xr * w2.x;
            acc[i].y += xr * w2.y;
        }
    }
    float2* P2 = (float2*)P;
#pragma unroll
    for (int i = 0; i < 8; ++i)
        P2[(size_t)(blockIdx.y * 32 + r0 + i) * n2 + c2] = acc[i];
}

// ---------------------------------------------------------------------------
// QKV finish: sum split-K partials + bias, RoPE (block-diag 2x2), q*scale.
// ---------------------------------------------------------------------------
__global__ __launch_bounds__(256) void qkv_finish(const float* __restrict__ P,
                                                  const float* __restrict__ bias,
                                                  const float* __restrict__ rot,
                                                  float* __restrict__ xqkv) {
    int t  = blockIdx.x * 256 + threadIdx.x;     // pair id, 32*2304 total
    int r  = t / (NQKV_ / 2);
    int cp = t - r * (NQKV_ / 2);
    int c0 = cp * 2;

    float v0 = bias[c0], v1 = bias[c0 + 1];
#pragma unroll
    for (int kc = 0; kc < NKC_; ++kc) {
        float2 pv = *(const float2*)&P[((size_t)(kc * 32 + r) * NQKV_) + c0];
        v0 += pv.x; v1 += pv.y;
    }
    if (c0 < (NH_ + NKV_) * HD_) {               // q and k sections get RoPE
        int j = (c0 & (HD_ - 1)) >> 1;           // head-local pair index
        float cs = rot[(2 * j) * HD_ + 2 * j];
        float sn = rot[(2 * j) * HD_ + 2 * j + 1];
        float o0 = v0 * cs - v1 * sn;
        float o1 = v0 * sn + v1 * cs;
        if (c0 < NH_ * HD_) { o0 *= SCALE_; o1 *= SCALE_; }   // fold q scale
        v0 = o0; v1 = o1;
    }
    *(float2*)&xqkv[(size_t)r * NQKV_ + c0] = make_float2(v0, v1);
}

// ---------------------------------------------------------------------------
// Flash-decode attention, R8: per block 256 rows = 4 tiles of 64, K/V staged
// through double-buffered LDS via async global_load_lds. All K/V LDS reads
// are wave-local rows (wave w owns rows [16w,16w+16) of each tile) -> only
// own-wave vmcnt waits; the two sc handoffs use raw s_barrier + lgkmcnt(0)
// so the DMA queue is never drained by a barrier. Online softmax across tiles.
// ---------------------------------------------------------------------------
__global__ __launch_bounds__(256) void attn_kernel(const float* __restrict__ xqkv,
                                                   const float* __restrict__ cache_k,
                                                   const float* __restrict__ cache_v,
                                                   const int* __restrict__ curp,
                                                   float* __restrict__ part_ctx,
                                                   float* __restrict__ part_ml) {
    __shared__ __align__(16) float kb[2][TROWS_ * HD_];   // 2 x 32 KB staging
    __shared__ __align__(16) float sc[GRP_][TROWS_];      // per-tile scores
    __shared__ float fbuf[GRP_ + 1];                      // per-tile rescale

    const int bid  = blockIdx.x;
    const int c    = bid & (NCHUNK_ - 1);
    const int kv   = (bid >> 4) & (NKV_ - 1);
    const int b    = bid >> 6;
    const int tid  = threadIdx.x;
    const int lane = tid & 63;
    const int wv   = tid >> 6;
    const int hl   = lane & 31;      // lane within half-wave (quad index)
    const int sub  = lane >> 5;      // row parity within pair

    const int cur   = curp[0];
    const int slot  = cur & (SW_ - 1);
    const int sbase = c * CHUNK_;
    const int r0    = wv * 16;       // this wave's rows within each tile

    const float4* qg4   = (const float4*)(xqkv + (size_t)b * NQKV_ + kv * (GRP_ * HD_));
    const float4* knew4 = (const float4*)(xqkv + (size_t)b * NQKV_ + NH_ * HD_ + kv * HD_);
    const float4* vnew4 = (const float4*)(xqkv + (size_t)b * NQKV_ + (NH_ + NKV_) * HD_ + kv * HD_);
    const float*  kcb   = cache_k + ((size_t)(b * NKV_ + kv) * SW_) * HD_;
    const float*  vcb   = cache_v + ((size_t)(b * NKV_ + kv) * SW_) * HD_;

    // q quads in registers (28 VGPR)
    float4 qreg[GRP_];
#pragma unroll
    for (int h = 0; h < GRP_; ++h) qreg[h] = qg4[h * 32 + hl];

    // prologue: DMA K tile 0 (own 16 rows, 8 calls of 2 rows each)
    {
        const float* kt = kcb + (size_t)(sbase) * HD_;
#pragma unroll
        for (int j = 0; j < 8; ++j)
            dma16(kt + (size_t)(r0 + 2 * j) * HD_ + lane * 4, &kb[0][(r0 + 2 * j) * HD_]);
    }

    float mr0 = -1e30f, lr0 = 0.f, mr1 = -1e30f, lr1 = 0.f;  // owner-wave m/l
    float2 acc2[GRP_];
#pragma unroll
    for (int h = 0; h < GRP_; ++h) acc2[h] = make_float2(0.f, 0.f);

#pragma unroll
    for (int t = 0; t < NT_; ++t) {
        const int cb  = t & 1;
        const int tb  = sbase + t * TROWS_;          // tile's global row base
        const int slr = slot - tb - r0;              // slot row rel. to own rows

        // K_t arrived (own DMA); fix ring-slot row in own region
        asm volatile("s_waitcnt vmcnt(0)" ::: "memory");
        if (slr >= 0 && slr < 16 && lane < 32)
            *(float4*)&kb[cb][(r0 + slr) * HD_ + lane * 4] = knew4[lane];

        // ---- QK^T on own 16 rows (2 rows/iter, DPP half-wave reduce) ------
#pragma unroll
        for (int i = 0; i < 8; ++i) {
            const int rl = r0 + 2 * i + sub;         // tile-local row
            float4 kq = *(const float4*)&kb[cb][rl * HD_ + hl * 4];
            float part[GRP_];
#pragma unroll
            for (int h = 0; h < GRP_; ++h)
                part[h] = qreg[h].x * kq.x + qreg[h].y * kq.y
                        + qreg[h].z * kq.z + qreg[h].w * kq.w;
#pragma unroll
            for (int h = 0; h < GRP_; ++h)
                part[h] = halfwave_allreduce(part[h]);
            if (hl == 0) {
                const bool v = (tb + rl <= cur);
#pragma unroll
                for (int h = 0; h < GRP_; ++h) sc[h][rl] = v ? part[h] : -1e30f;
            }
        }
        asm volatile("s_waitcnt lgkmcnt(0)" ::: "memory");
        __builtin_amdgcn_s_barrier();               // sc raw scores visible

        // V_t DMA into kb[cb] (own rows; own K reads are done)
        {
            const float* vt = vcb + (size_t)tb * HD_;
#pragma unroll
            for (int j = 0; j < 8; ++j)
                dma16(vt + (size_t)(r0 + 2 * j) * HD_ + lane * 4, &kb[cb][(r0 + 2 * j) * HD_]);
        }

        // ---- online softmax: wave w owns heads {w, w+4} -------------------
        {
            float v = sc[wv][lane];
            float m = v;
#pragma unroll
            for (int off = 32; off; off >>= 1) m = fmaxf(m, __shfl_xor(m, off));
            float mn = fmaxf(mr0, m);
            float e = __expf(v - mn);
            sc[wv][lane] = e;
            float s = e;
#pragma unroll
            for (int off = 32; off; off >>= 1) s += __shfl_xor(s, off);
            float f = __expf(mr0 - mn);
            lr0 = lr0 * f + s; mr0 = mn;
            if (lane == 0) fbuf[wv] = f;
        }
        if (wv < 3) {
            float v = sc[wv + 4][lane];
            float m = v;
#pragma unroll
            for (int off = 32; off; off >>= 1) m = fmaxf(m, __shfl_xor(m, off));
            float mn = fmaxf(mr1, m);
            float e = __expf(v - mn);
            sc[wv + 4][lane] = e;
            float s = e;
#pragma unroll
            for (int off = 32; off; off >>= 1) s += __shfl_xor(s, off);
            float f = __expf(mr1 - mn);
            lr1 = lr1 * f + s; mr1 = mn;
            if (lane == 0) fbuf[wv + 4] = f;
        }
        asm volatile("s_waitcnt lgkmcnt(0)" ::: "memory");
        __builtin_amdgcn_s_barrier();               // exp weights + fbuf visible

        // prefetch K_{t+1} into the other buffer; counted wait for V_t only
        if (t < NT_ - 1) {
            const float* kt = kcb + (size_t)(tb + TROWS_) * HD_;
#pragma unroll
            for (int j = 0; j < 8; ++j)
                dma16(kt + (size_t)(r0 + 2 * j) * HD_ + lane * 4, &kb[cb ^ 1][(r0 + 2 * j) * HD_]);
            asm volatile("s_waitcnt vmcnt(8)" ::: "memory");   // V_t (oldest 8) done
        } else {
            asm volatile("s_waitcnt vmcnt(0)" ::: "memory");
        }
        if (slr >= 0 && slr < 16 && lane < 32)      // fix ring-slot V row
            *(float4*)&kb[cb][(r0 + slr) * HD_ + lane * 4] = vnew4[lane];

        // ---- rescale + PV on own 16 rows ---------------------------------
#pragma unroll
        for (int h = 0; h < GRP_; ++h) {
            float f = fbuf[h];
            acc2[h].x *= f; acc2[h].y *= f;
        }
#pragma unroll
        for (int it = 0; it < 4; ++it) {
            const int s = r0 + it * 4;
            float2 vvv[4];
#pragma unroll
            for (int r = 0; r < 4; ++r)
                vvv[r] = *(const float2*)&kb[cb][(s + r) * HD_ + lane * 2];
#pragma unroll
            for (int h = 0; h < GRP_; ++h) {
                float4 pp = *(const float4*)&sc[h][s];
                acc2[h].x += pp.x * vvv[0].x + pp.y * vvv[1].x + pp.z * vvv[2].x + pp.w * vvv[3].x;
                acc2[h].y += pp.x * vvv[0].y + pp.y * vvv[1].y + pp.z * vvv[2].y + pp.w * vvv[3].y;
            }
        }
    }

    // ---- epilogue: sum 4 waves' acc via LDS (reuse kb[0], V_2 is dead) ----
    float2* cbuf = (float2*)&kb[0][0];              // [4][448] float2
#pragma unroll
    for (int h = 0; h < GRP_; ++h)
        cbuf[wv * (GRP_ * 64) + h * 64 + lane] = acc2[h];
    asm volatile("s_waitcnt lgkmcnt(0)" ::: "memory");
    __builtin_amdgcn_s_barrier();

    float2* pc2 = (float2*)part_ctx;
    for (int t2 = tid; t2 < GRP_ * 64; t2 += 256) {   // strided LOOP (R4 lesson)
        float2 a = cbuf[t2], bb = cbuf[448 + t2],
               cc2 = cbuf[896 + t2], d = cbuf[1344 + t2];
        float2 r = make_float2(a.x + bb.x + cc2.x + d.x, a.y + bb.y + cc2.y + d.y);
        pc2[(size_t)bid * (GRP_ * 64) + t2] = r;
    }
    if (lane == 0) {
        part_ml[bid * 14 + wv]     = mr0;
        part_ml[bid * 14 + 7 + wv] = lr0;
        if (wv < 3) {
            part_ml[bid * 14 + wv + 4]     = mr1;
            part_ml[bid * 14 + 7 + wv + 4] = lr1;
        }
    }
}

// ---------------------------------------------------------------------------
// Combine the 16 chunk partials: one block per (g, head); thread = column.
// ---------------------------------------------------------------------------
__global__ __launch_bounds__(128) void combine_kernel(const float* __restrict__ part_ctx,
                                                      const float* __restrict__ part_ml,
                                                      float* __restrict__ ctx) {
    const int g = blockIdx.x;             // b*NKV + kv
    const int h = blockIdx.y;             // head within group
    const int d = threadIdx.x;            // column 0..127

    float M = -1e30f;
    for (int cc = 0; cc < NCHUNK_; ++cc)
        M = fmaxf(M, part_ml[(g * NCHUNK_ + cc) * 14 + h]);   // uniform -> scalar

    float L = 0.f, s = 0.f;
    for (int cc = 0; cc < NCHUNK_; ++cc) {
        float e = __expf(part_ml[(g * NCHUNK_ + cc) * 14 + h] - M);
        L += part_ml[(g * NCHUNK_ + cc) * 14 + 7 + h] * e;
        s += part_ctx[(size_t)(g * NCHUNK_ + cc) * (GRP_ * HD_) + h * HD_ + d] * e;
    }
    const int b = g >> 2, kv = g & 3;
    ctx[(size_t)b * D_ + kv * (GRP_ * HD_) + h * HD_ + d] = s / L;
}

// ---------------------------------------------------------------------------
// Final reduce of O-projection split-K partials into d_out.
// ---------------------------------------------------------------------------
__global__ __launch_bounds__(256) void out_finish(const float* __restrict__ P,
                                                  float* __restrict__ out) {
    int t = blockIdx.x * 256 + threadIdx.x;   // < 32*3584
    float s = 0.f;
#pragma unroll
    for (int kc = 0; kc < NKC_; ++kc) s += P[(size_t)kc * (32 * D_) + t];
    out[t] = s;
}

// ---------------------------------------------------------------------------
extern "C" void kernel_launch(void* const* d_in, const int* in_sizes, int n_in,
                              void* d_out, int out_size, void* d_ws, size_t ws_size,
                              hipStream_t stream) {
    const float* x    = (const float*)d_in[0];
    const float* wqkv = (const float*)d_in[1];
    const float* bias = (const float*)d_in[2];
    const float* wo   = (const float*)d_in[3];
    const float* rot  = (const float*)d_in[4];
    const float* ck   = (const float*)d_in[5];
    const float* cv   = (const float*)d_in[6];
    const int*   cur  = (const int*)d_in[7];
    float* out = (float*)d_out;
    float* ws  = (float*)d_ws;

    // workspace layout (floats) — no aliasing, ~18 MB total
    float* partials = ws;                                        // 2,359,296
    float* xqkv     = partials + (size_t)NKC_ * 32 * NQKV_;      //   147,456
    float* pctx     = xqkv + (size_t)B_ * NQKV_;                 // 1,835,008
    float* pml      = pctx + (size_t)B_ * NKV_ * NCHUNK_ * GRP_ * HD_; // 28,672
    float* ctx      = pml  + (size_t)B_ * NKV_ * NCHUNK_ * 14;   //   114,688

    // 1) QKV projection (split-K partials)
    proj_kernel<<<dim3(NQKV_ / 128, NKC_), 256, 0, stream>>>(x, wqkv, partials, NQKV_);
    // 2) bias + RoPE + q-scale
    qkv_finish<<<(B_ * NQKV_ / 2) / 256, 256, 0, stream>>>(partials, bias, rot, xqkv);
    // 3) flash-decode attention over (b, kv, 256-row chunk)
    attn_kernel<<<B_ * NKV_ * NCHUNK_, 256, 0, stream>>>(xqkv, ck, cv, cur, pctx, pml);
    // 4) combine chunks — one block per (g, head)
    combine_kernel<<<dim3(B_ * NKV_, GRP_), 128, 0, stream>>>(pctx, pml, ctx);
    // 5) output projection (split-K partials, reuse buffer)
    proj_kernel<<<dim3(D_ / 128, NKC_), 256, 0, stream>>>(ctx, wo, partials, D_);
    // 6) reduce into d_out
    out_finish<<<(B_ * D_) / 256, 256, 0, stream>>>(partials, out);
}

// Round 9
// 246.820 us; speedup vs baseline: 1.1847x; 1.1847x over previous
//
#include <hip/hip_runtime.h>
#include <hip/hip_bf16.h>

// Problem constants (fixed by the reference)
#define B_   32
#define D_   3584
#define NH_  28
#define NKV_ 4
#define HD_  128
#define SW_  4096
#define GRP_ 7                    // NH/NKV
#define NQKV_ 4608                // (NH+2*NKV)*HD
#define SCALE_ 0.08838834764831845f  // HD^-0.5
#define NKC_ 16                   // split-K chunks for projections
#define KC_  224                  // D_/NKC_
#define NCHUNK_ 64                // PV chunks per (b,kv): 64 chunks x 64 rows
#define SCPAD_ 8                  // scT row stride (7 heads + 1 pad)

// ---------------------------------------------------------------------------
// Half-wave (32-lane) all-reduce sum, VALU-DPP for 4 of 5 steps (verified R7).
// ---------------------------------------------------------------------------
__device__ __forceinline__ float halfwave_allreduce(float x) {
    x += __int_as_float(__builtin_amdgcn_mov_dpp(__float_as_int(x), 0xB1, 0xF, 0xF, true));
    x += __int_as_float(__builtin_amdgcn_mov_dpp(__float_as_int(x), 0x4E, 0xF, 0xF, true));
    x += __int_as_float(__builtin_amdgcn_mov_dpp(__float_as_int(x), 0x141, 0xF, 0xF, true));
    x += __int_as_float(__builtin_amdgcn_mov_dpp(__float_as_int(x), 0x140, 0xF, 0xF, true));
    x += __int_as_float(__builtin_amdgcn_ds_swizzle(__float_as_int(x), 0x401F));
    return x;
}

// ---------------------------------------------------------------------------
// Split-K projection: P[kc][32][N] = X[32][3584] @ W[3584][N]  (partial sums)
// ---------------------------------------------------------------------------
__global__ __launch_bounds__(256) void proj_kernel(const float* __restrict__ X,
                                                   const float* __restrict__ W,
                                                   float* __restrict__ P, int N) {
    const int lane = threadIdx.x & 63;
    const int wv   = __builtin_amdgcn_readfirstlane(threadIdx.x >> 6);
    const int r0   = wv * 8;
    const int c2   = blockIdx.x * 64 + lane;   // float2 column index
    const int k0   = blockIdx.y * KC_;
    const int n2   = N >> 1;
    const float2* __restrict__ W2 = (const float2*)W;

    float2 acc[8];
#pragma unroll
    for (int i = 0; i < 8; ++i) acc[i] = make_float2(0.f, 0.f);

#pragma unroll 8
    for (int k = k0; k < k0 + KC_; ++k) {
        float2 w2 = W2[(size_t)k * n2 + c2];
#pragma unroll
        for (int i = 0; i < 8; ++i) {
            float xr = X[(size_t)(r0 + i) * D_ + k];   // wave-uniform -> s_load
            acc[i].x += xr * w2.x;
            acc[i].y += xr * w2.y;
        }
    }
    float2* P2 = (float2*)P;
#pragma unroll
    for (int i = 0; i < 8; ++i)
        P2[(size_t)(blockIdx.y * 32 + r0 + i) * n2 + c2] = acc[i];
}

// ---------------------------------------------------------------------------
// QKV finish: sum split-K partials + bias, RoPE (block-diag 2x2), q*scale.
// ---------------------------------------------------------------------------
__global__ __launch_bounds__(256) void qkv_finish(const float* __restrict__ P,
                                                  const float* __restrict__ bias,
                                                  const float* __restrict__ rot,
                                                  float* __restrict__ xqkv) {
    int t  = blockIdx.x * 256 + threadIdx.x;     // pair id, 32*2304 total
    int r  = t / (NQKV_ / 2);
    int cp = t - r * (NQKV_ / 2);
    int c0 = cp * 2;

    float v0 = bias[c0], v1 = bias[c0 + 1];
#pragma unroll
    for (int kc = 0; kc < NKC_; ++kc) {
        float2 pv = *(const float2*)&P[((size_t)(kc * 32 + r) * NQKV_) + c0];
        v0 += pv.x; v1 += pv.y;
    }
    if (c0 < (NH_ + NKV_) * HD_) {               // q and k sections get RoPE
        int j = (c0 & (HD_ - 1)) >> 1;           // head-local pair index
        float cs = rot[(2 * j) * HD_ + 2 * j];
        float sn = rot[(2 * j) * HD_ + 2 * j + 1];
        float o0 = v0 * cs - v1 * sn;
        float o1 = v0 * sn + v1 * cs;
        if (c0 < NH_ * HD_) { o0 *= SCALE_; o1 *= SCALE_; }   // fold q scale
        v0 = o0; v1 = o1;
    }
    *(float2*)&xqkv[(size_t)r * NQKV_ + c0] = make_float2(v0, v1);
}

// ---------------------------------------------------------------------------
// QK^T streamer: grid = B*NKV*64 tiles of 64 rows; wave owns 16 rows.
// Half-wave split loads (coalesced 1KB/wave-instr), DPP reduce (R7-verified),
// masked raw scores written TRANSPOSED to scT[row][8] (coalesced stores).
// No __syncthreads; waves fully independent -> high occupancy streaming.
// ---------------------------------------------------------------------------
__global__ __launch_bounds__(256) void qk_kernel(const float* __restrict__ xqkv,
                                                 const float* __restrict__ cache_k,
                                                 const int* __restrict__ curp,
                                                 float* __restrict__ scT) {
    __shared__ float scw[4][128];     // per-wave [16 rows][8 cols] transpose buf

    const int bid  = blockIdx.x;
    const int t    = bid & 63;
    const int kv   = (bid >> 6) & (NKV_ - 1);
    const int b    = bid >> 8;
    const int tid  = threadIdx.x;
    const int lane = tid & 63;
    const int wv   = tid >> 6;
    const int hl   = lane & 31;
    const int sub  = lane >> 5;

    const int cur  = curp[0];
    const int slot = cur & (SW_ - 1);
    const int rb   = t * 64 + wv * 16;           // wave's global row base

    const float4* qg4   = (const float4*)(xqkv + (size_t)b * NQKV_ + kv * (GRP_ * HD_));
    const float4* knew4 = (const float4*)(xqkv + (size_t)b * NQKV_ + NH_ * HD_ + kv * HD_);
    const float4* kct4  = (const float4*)(cache_k + ((size_t)(b * NKV_ + kv) * SW_ + rb) * HD_);

    float4 qreg[GRP_];
#pragma unroll
    for (int h = 0; h < GRP_; ++h) qreg[h] = qg4[h * 32 + hl];

#pragma unroll
    for (int i = 0; i < 8; ++i) {
        const int gs = rb + 2 * i + sub;
        const float4* kp = (gs == slot) ? (knew4 + hl)
                                        : (kct4 + (size_t)(2 * i) * 32 + lane);
        float4 kq = *kp;

        float part[GRP_];
#pragma unroll
        for (int h = 0; h < GRP_; ++h)
            part[h] = qreg[h].x * kq.x + qreg[h].y * kq.y
                    + qreg[h].z * kq.z + qreg[h].w * kq.w;
#pragma unroll
        for (int h = 0; h < GRP_; ++h)
            part[h] = halfwave_allreduce(part[h]);

        // static select chain: lane hl picks part[hl] (no runtime reg index)
        float val = part[0];
        if (hl == 1) val = part[1];
        if (hl == 2) val = part[2];
        if (hl == 3) val = part[3];
        if (hl == 4) val = part[4];
        if (hl == 5) val = part[5];
        if (hl == 6) val = part[6];
        val = (gs <= cur) ? val : -1e30f;
        if (hl < 7) scw[wv][(2 * i + sub) * SCPAD_ + hl] = val;
    }
    asm volatile("s_waitcnt lgkmcnt(0)" ::: "memory");   // same-wave LDS visibility

    // coalesced transposed store: 16 rows x 8 cols = 128 dwords (col7 = pad)
    float f0 = scw[wv][lane];
    float f1 = scw[wv][64 + lane];
    float* outp = scT + (((size_t)(b * NKV_ + kv) * SW_) + rb) * SCPAD_;
    outp[lane]      = f0;
    outp[64 + lane] = f1;
}

// ---------------------------------------------------------------------------
// PV streamer: grid = B*NKV*16 blocks; wave owns 64 rows (one chunk).
// Softmax per head via 64-lane butterfly from scT; exp weights staged in
// wave-private LDS (no barrier); PV = R5's verified float4-p x float2-V loop.
// ---------------------------------------------------------------------------
__global__ __launch_bounds__(256) void pv_kernel(const float* __restrict__ xqkv,
                                                 const float* __restrict__ cache_v,
                                                 const int* __restrict__ curp,
                                                 const float* __restrict__ scT,
                                                 float* __restrict__ part_ctx,
                                                 float* __restrict__ part_ml) {
    __shared__ float scp[4][GRP_][64];   // per-wave exp weights, 7 KB

    const int bid  = blockIdx.x;
    const int c16  = bid & 15;
    const int kv   = (bid >> 4) & (NKV_ - 1);
    const int b    = bid >> 6;
    const int tid  = threadIdx.x;
    const int lane = tid & 63;
    const int wv   = tid >> 6;

    const int cur  = curp[0];
    const int slot = cur & (SW_ - 1);
    const int rb   = c16 * 256 + wv * 64;            // wave's global row base
    const int cid  = (b * NKV_ + kv) * NCHUNK_ + c16 * 4 + wv;

    // ---- load own row's 7 scores (raw, already masked by qk_kernel) -------
    const float* srow = scT + (((size_t)(b * NKV_ + kv) * SW_) + rb + lane) * SCPAD_;
    float4 sa = *(const float4*)srow;
    float4 sb = *(const float4*)(srow + 4);
    float s[GRP_] = {sa.x, sa.y, sa.z, sa.w, sb.x, sb.y, sb.z};

    // ---- softmax per head over the wave's 64 rows --------------------------
    float m[GRP_], l[GRP_];
#pragma unroll
    for (int h = 0; h < GRP_; ++h) {
        float mx = s[h];
#pragma unroll
        for (int off = 32; off; off >>= 1) mx = fmaxf(mx, __shfl_xor(mx, off));
        m[h] = mx;
        float e = __expf(s[h] - mx);
        scp[wv][h][lane] = e;
        float ls = e;
#pragma unroll
        for (int off = 32; off; off >>= 1) ls += __shfl_xor(ls, off);
        l[h] = ls;
    }
    asm volatile("s_waitcnt lgkmcnt(0)" ::: "memory");   // scp visible (same wave)

    // ---- PV: iterate 64 rows, 4 at a time; coalesced float2 V loads -------
    const float2* vcb   = (const float2*)(cache_v + ((size_t)(b * NKV_ + kv) * SW_) * HD_);
    const float2* vnew2 = (const float2*)(xqkv + (size_t)b * NQKV_ + (NH_ + NKV_) * HD_ + kv * HD_);

    float2 acc2[GRP_];
#pragma unroll
    for (int h = 0; h < GRP_; ++h) acc2[h] = make_float2(0.f, 0.f);

#pragma unroll 2
    for (int it = 0; it < 16; ++it) {
        const int s0 = it * 4;
        float2 vv[4];
#pragma unroll
        for (int r = 0; r < 4; ++r) {
            const int gs = rb + s0 + r;
            const float2* vp = (gs == slot) ? vnew2 : vcb + (size_t)gs * (HD_ / 2);
            vv[r] = vp[lane];
        }
#pragma unroll
        for (int h = 0; h < GRP_; ++h) {
            float4 pp = *(const float4*)&scp[wv][h][s0];
            acc2[h].x += pp.x * vv[0].x + pp.y * vv[1].x + pp.z * vv[2].x + pp.w * vv[3].x;
            acc2[h].y += pp.x * vv[0].y + pp.y * vv[1].y + pp.z * vv[2].y + pp.w * vv[3].y;
        }
    }

    // ---- store partials (coalesced float2), m/l scalars --------------------
    float2* pc2 = (float2*)(part_ctx + (size_t)cid * (GRP_ * HD_));
#pragma unroll
    for (int h = 0; h < GRP_; ++h)
        pc2[h * 64 + lane] = acc2[h];
    if (lane == 0) {
#pragma unroll
        for (int h = 0; h < GRP_; ++h) {
            part_ml[cid * 14 + h]     = m[h];
            part_ml[cid * 14 + 7 + h] = l[h];
        }
    }
}

// ---------------------------------------------------------------------------
// Combine the 64 chunk partials: one block per (g, head); thread = column.
// ---------------------------------------------------------------------------
__global__ __launch_bounds__(128) void combine_kernel(const float* __restrict__ part_ctx,
                                                      const float* __restrict__ part_ml,
                                                      float* __restrict__ ctx) {
    const int g = blockIdx.x;             // b*NKV + kv
    const int h = blockIdx.y;             // head within group
    const int d = threadIdx.x;            // column 0..127

    float M = -1e30f;
    for (int cc = 0; cc < NCHUNK_; ++cc)
        M = fmaxf(M, part_ml[(g * NCHUNK_ + cc) * 14 + h]);   // uniform -> scalar

    float L = 0.f, s = 0.f;
    for (int cc = 0; cc < NCHUNK_; ++cc) {
        float e = __expf(part_ml[(g * NCHUNK_ + cc) * 14 + h] - M);
        L += part_ml[(g * NCHUNK_ + cc) * 14 + 7 + h] * e;
        s += part_ctx[(size_t)(g * NCHUNK_ + cc) * (GRP_ * HD_) + h * HD_ + d] * e;
    }
    const int b = g >> 2, kv = g & 3;
    ctx[(size_t)b * D_ + kv * (GRP_ * HD_) + h * HD_ + d] = s / L;
}

// ---------------------------------------------------------------------------
// Final reduce of O-projection split-K partials into d_out.
// ---------------------------------------------------------------------------
__global__ __launch_bounds__(256) void out_finish(const float* __restrict__ P,
                                                  float* __restrict__ out) {
    int t = blockIdx.x * 256 + threadIdx.x;   // < 32*3584
    float s = 0.f;
#pragma unroll
    for (int kc = 0; kc < NKC_; ++kc) s += P[(size_t)kc * (32 * D_) + t];
    out[t] = s;
}

// ---------------------------------------------------------------------------
extern "C" void kernel_launch(void* const* d_in, const int* in_sizes, int n_in,
                              void* d_out, int out_size, void* d_ws, size_t ws_size,
                              hipStream_t stream) {
    const float* x    = (const float*)d_in[0];
    const float* wqkv = (const float*)d_in[1];
    const float* bias = (const float*)d_in[2];
    const float* wo   = (const float*)d_in[3];
    const float* rot  = (const float*)d_in[4];
    const float* ck   = (const float*)d_in[5];
    const float* cv   = (const float*)d_in[6];
    const int*   cur  = (const int*)d_in[7];
    float* out = (float*)d_out;
    float* ws  = (float*)d_ws;

    // workspace layout (floats) — ~42 MB total, no aliasing
    float* partials = ws;                                        // 2,359,296
    float* xqkv     = partials + (size_t)NKC_ * 32 * NQKV_;      //   147,456
    float* scT      = xqkv + (size_t)B_ * NQKV_;                 // 4,194,304
    float* pctx     = scT + (size_t)B_ * NKV_ * SW_ * SCPAD_;    // 3,670,016
    float* pml      = pctx + (size_t)B_ * NKV_ * NCHUNK_ * GRP_ * HD_; // 57,344
    float* ctx      = pml  + (size_t)B_ * NKV_ * NCHUNK_ * 14;   //   114,688

    // 1) QKV projection (split-K partials)
    proj_kernel<<<dim3(NQKV_ / 128, NKC_), 256, 0, stream>>>(x, wqkv, partials, NQKV_);
    // 2) bias + RoPE + q-scale
    qkv_finish<<<(B_ * NQKV_ / 2) / 256, 256, 0, stream>>>(partials, bias, rot, xqkv);
    // 3a) QK^T streamer -> transposed score buffer
    qk_kernel<<<B_ * NKV_ * 64, 256, 0, stream>>>(xqkv, ck, cur, scT);
    // 3b) softmax + PV streamer -> 64-row partials
    pv_kernel<<<B_ * NKV_ * 16, 256, 0, stream>>>(xqkv, cv, cur, scT, pctx, pml);
    // 4) combine chunks — one block per (g, head)
    combine_kernel<<<dim3(B_ * NKV_, GRP_), 128, 0, stream>>>(pctx, pml, ctx);
    // 5) output projection (split-K partials, reuse buffer)
    proj_kernel<<<dim3(D_ / 128, NKC_), 256, 0, stream>>>(ctx, wo, partials, D_);
    // 6) reduce into d_out
    out_finish<<<(B_ * D_) / 256, 256, 0, stream>>>(partials, out);
}

// Round 10
// 200.631 us; speedup vs baseline: 1.4575x; 1.2302x over previous
//
#include <hip/hip_runtime.h>
#include <hip/hip_bf16.h>

// Problem constants (fixed by the reference)
#define B_   32
#define D_   3584
#define NH_  28
#define NKV_ 4
#define HD_  128
#define SW_  4096
#define GRP_ 7                    // NH/NKV
#define NQKV_ 4608                // (NH+2*NKV)*HD
#define SCALE_ 0.08838834764831845f  // HD^-0.5
#define NKC_ 16                   // split-K chunks for projections
#define KC_  224                  // D_/NKC_
#define NCHUNK_ 64                // attention s-chunks (grid = 32*4*64 = 8192 blocks)
#define CHUNK_ 64                 // SW_/NCHUNK_

// ---------------------------------------------------------------------------
// Half-wave (32-lane) all-reduce sum, VALU-DPP for 4 of 5 steps.
//  xor1: quad_perm(1,0,3,2)=0xB1   xor2: quad_perm(2,3,0,1)=0x4E
//  xor4: row_half_mirror 0x141 (== xor7; quads already uniform)
//  xor8: row_mirror      0x140 (== xor15; 8-groups already uniform)
//  xor16: ds_swizzle BitMode 0x401F (applies within each 32-lane group)
// ---------------------------------------------------------------------------
__device__ __forceinline__ float halfwave_allreduce(float x) {
    x += __int_as_float(__builtin_amdgcn_mov_dpp(__float_as_int(x), 0xB1, 0xF, 0xF, true));
    x += __int_as_float(__builtin_amdgcn_mov_dpp(__float_as_int(x), 0x4E, 0xF, 0xF, true));
    x += __int_as_float(__builtin_amdgcn_mov_dpp(__float_as_int(x), 0x141, 0xF, 0xF, true));
    x += __int_as_float(__builtin_amdgcn_mov_dpp(__float_as_int(x), 0x140, 0xF, 0xF, true));
    x += __int_as_float(__builtin_amdgcn_ds_swizzle(__float_as_int(x), 0x401F));
    return x;
}

// ---------------------------------------------------------------------------
// Split-K projection: P[kc][32][N] = X[32][3584] @ W[3584][N]  (partial sums)
// ---------------------------------------------------------------------------
__global__ __launch_bounds__(256) void proj_kernel(const float* __restrict__ X,
                                                   const float* __restrict__ W,
                                                   float* __restrict__ P, int N) {
    const int lane = threadIdx.x & 63;
    const int wv   = __builtin_amdgcn_readfirstlane(threadIdx.x >> 6);
    const int r0   = wv * 8;
    const int c2   = blockIdx.x * 64 + lane;   // float2 column index
    const int k0   = blockIdx.y * KC_;
    const int n2   = N >> 1;
    const float2* __restrict__ W2 = (const float2*)W;

    float2 acc[8];
#pragma unroll
    for (int i = 0; i < 8; ++i) acc[i] = make_float2(0.f, 0.f);

#pragma unroll 8
    for (int k = k0; k < k0 + KC_; ++k) {
        float2 w2 = W2[(size_t)k * n2 + c2];
#pragma unroll
        for (int i = 0; i < 8; ++i) {
            float xr = X[(size_t)(r0 + i) * D_ + k];   // wave-uniform -> s_load
            acc[i].x += xr * w2.x;
            acc[i].y += xr * w2.y;
        }
    }
    float2* P2 = (float2*)P;
#pragma unroll
    for (int i = 0; i < 8; ++i)
        P2[(size_t)(blockIdx.y * 32 + r0 + i) * n2 + c2] = acc[i];
}

// ---------------------------------------------------------------------------
// QKV finish: sum split-K partials + bias, RoPE (block-diag 2x2), q*scale.
// ---------------------------------------------------------------------------
__global__ __launch_bounds__(256) void qkv_finish(const float* __restrict__ P,
                                                  const float* __restrict__ bias,
                                                  const float* __restrict__ rot,
                                                  float* __restrict__ xqkv) {
    int t  = blockIdx.x * 256 + threadIdx.x;     // pair id, 32*2304 total
    int r  = t / (NQKV_ / 2);
    int cp = t - r * (NQKV_ / 2);
    int c0 = cp * 2;

    float v0 = bias[c0], v1 = bias[c0 + 1];
#pragma unroll
    for (int kc = 0; kc < NKC_; ++kc) {
        float2 pv = *(const float2*)&P[((size_t)(kc * 32 + r) * NQKV_) + c0];
        v0 += pv.x; v1 += pv.y;
    }
    if (c0 < (NH_ + NKV_) * HD_) {               // q and k sections get RoPE
        int j = (c0 & (HD_ - 1)) >> 1;           // head-local pair index
        float cs = rot[(2 * j) * HD_ + 2 * j];
        float sn = rot[(2 * j) * HD_ + 2 * j + 1];
        float o0 = v0 * cs - v1 * sn;
        float o1 = v0 * sn + v1 * cs;
        if (c0 < NH_ * HD_) { o0 *= SCALE_; o1 *= SCALE_; }   // fold q scale
        v0 = o0; v1 = o1;
    }
    *(float2*)&xqkv[(size_t)r * NQKV_ + c0] = make_float2(v0, v1);
}

// ---------------------------------------------------------------------------
// Flash-decode attention over one (b, kv, s-chunk of 64).
// Roofline configuration (R7): up-front q/K/V loads, DPP half-wave reduce,
// per-head butterfly softmax, coalesced PV from registers. Delivered read BW
// ~3.4 TB/s = measured per-direction ceiling (m13 copy = 3.15 TB/s/dir).
// ---------------------------------------------------------------------------
__global__ __launch_bounds__(256, 2) void attn_kernel(const float* __restrict__ xqkv,
                                                      const float* __restrict__ cache_k,
                                                      const float* __restrict__ cache_v,
                                                      const int* __restrict__ curp,
                                                      float* __restrict__ part_ctx,
                                                      float* __restrict__ part_ml) {
    __shared__ __align__(16) float sc[GRP_][CHUNK_];        // scores -> exp weights
    __shared__ __align__(16) float2 ctxbuf[4][GRP_ * 64];   // 14336 B

    const int bid  = blockIdx.x;
    const int c    = bid & (NCHUNK_ - 1);
    const int kv   = (bid >> 6) & (NKV_ - 1);
    const int b    = bid >> 8;
    const int tid  = threadIdx.x;
    const int lane = tid & 63;
    const int wv   = tid >> 6;
    const int hl   = lane & 31;      // lane within half-wave (quad index)
    const int sub  = lane >> 5;      // which half (row parity)

    const int cur   = curp[0];
    const int slot  = cur & (SW_ - 1);
    const int sbase = c * CHUNK_;

    const float4* qg4   = (const float4*)(xqkv + (size_t)b * NQKV_ + kv * (GRP_ * HD_));
    const float4* knew4 = (const float4*)(xqkv + (size_t)b * NQKV_ + NH_ * HD_ + kv * HD_);
    const float4* kct4  = (const float4*)(cache_k + ((size_t)(b * NKV_ + kv) * SW_ + sbase) * HD_);
    const float2* vcb   = (const float2*)(cache_v + ((size_t)(b * NKV_ + kv) * SW_) * HD_);
    const float2* vnew2 = (const float2*)(xqkv + (size_t)b * NQKV_ + (NH_ + NKV_) * HD_ + kv * HD_);

    const int rA = wv * 16;          // this wave's 16 rows (for QK^T and PV)

    // ---- issue ALL loads up front (q: 7, K: 8, V: 16 -> ~31 in flight) ----
    float4 qreg[GRP_];
#pragma unroll
    for (int h = 0; h < GRP_; ++h) qreg[h] = qg4[h * 32 + hl];

    float4 kq[8];
#pragma unroll
    for (int i = 0; i < 8; ++i) {
        const int gs = sbase + rA + 2 * i + sub;
        const float4* kp = (gs == slot) ? (knew4 + hl)
                                        : (kct4 + (size_t)(rA + 2 * i) * 32 + lane);
        kq[i] = *kp;
    }
    float2 vv[16];
#pragma unroll
    for (int r = 0; r < 16; ++r) {
        const int gsv = sbase + rA + r;
        const float2* vp = (gsv == slot) ? vnew2 : vcb + (size_t)gsv * (HD_ / 2);
        vv[r] = vp[lane];
    }

    // ---- QK^T from registers: 2 rows per iter, DPP half-wave reduce -------
#pragma unroll
    for (int i = 0; i < 8; ++i) {
        const int rl = rA + 2 * i + sub;       // local row this half covers
        const int gs = sbase + rl;

        float part[GRP_];
#pragma unroll
        for (int h = 0; h < GRP_; ++h)
            part[h] = qreg[h].x * kq[i].x + qreg[h].y * kq[i].y
                    + qreg[h].z * kq[i].z + qreg[h].w * kq[i].w;
#pragma unroll
        for (int h = 0; h < GRP_; ++h)
            part[h] = halfwave_allreduce(part[h]);
        if (hl == 0) {
            const bool v = (gs <= cur);
#pragma unroll
            for (int h = 0; h < GRP_; ++h) sc[h][rl] = v ? part[h] : -1e30f;
        }
    }
    __syncthreads();

    // ---- softmax per head: wave w handles heads w and w+4 -----------------
    for (int h = wv; h < GRP_; h += 4) {
        float v = sc[h][lane];
        float m = v;
#pragma unroll
        for (int off = 32; off; off >>= 1) m = fmaxf(m, __shfl_xor(m, off));
        float e = __expf(v - m);
        sc[h][lane] = e;
        float s = e;
#pragma unroll
        for (int off = 32; off; off >>= 1) s += __shfl_xor(s, off);
        if (lane == 0) {
            part_ml[bid * 14 + h]     = m;
            part_ml[bid * 14 + 7 + h] = s;
        }
    }
    __syncthreads();

    // ---- PV from preloaded registers: wave owns rows [rA, rA+16) ----------
    float2 acc2[GRP_];
#pragma unroll
    for (int h = 0; h < GRP_; ++h) acc2[h] = make_float2(0.f, 0.f);

#pragma unroll
    for (int it = 0; it < 4; ++it) {
        const int s = rA + it * 4;
#pragma unroll
        for (int h = 0; h < GRP_; ++h) {
            float4 pp = *(const float4*)&sc[h][s];
            acc2[h].x += pp.x * vv[it * 4 + 0].x + pp.y * vv[it * 4 + 1].x
                       + pp.z * vv[it * 4 + 2].x + pp.w * vv[it * 4 + 3].x;
            acc2[h].y += pp.x * vv[it * 4 + 0].y + pp.y * vv[it * 4 + 1].y
                       + pp.z * vv[it * 4 + 2].y + pp.w * vv[it * 4 + 3].y;
        }
    }

#pragma unroll
    for (int h = 0; h < GRP_; ++h)
        ctxbuf[wv][h * 64 + lane] = acc2[h];
    __syncthreads();

    // epilogue: strided LOOP over 448 float2 (R4 bugfix — keep as loop!)
    float2* pc2 = (float2*)part_ctx;
    for (int t2 = tid; t2 < GRP_ * 64; t2 += 256) {
        float2 a = ctxbuf[0][t2], bb = ctxbuf[1][t2],
               cc2 = ctxbuf[2][t2], d = ctxbuf[3][t2];
        float2 r = make_float2(a.x + bb.x + cc2.x + d.x, a.y + bb.y + cc2.y + d.y);
        pc2[(size_t)bid * (GRP_ * 64) + t2] = r;
    }
}

// ---------------------------------------------------------------------------
// Combine the 64 chunk partials: one block per (g, head); thread = column.
// ---------------------------------------------------------------------------
__global__ __launch_bounds__(128) void combine_kernel(const float* __restrict__ part_ctx,
                                                      const float* __restrict__ part_ml,
                                                      float* __restrict__ ctx) {
    const int g = blockIdx.x;             // b*NKV + kv
    const int h = blockIdx.y;             // head within group
    const int d = threadIdx.x;            // column 0..127

    float M = -1e30f;
    for (int cc = 0; cc < NCHUNK_; ++cc)
        M = fmaxf(M, part_ml[(g * NCHUNK_ + cc) * 14 + h]);   // uniform -> scalar

    float L = 0.f, s = 0.f;
    for (int cc = 0; cc < NCHUNK_; ++cc) {
        float e = __expf(part_ml[(g * NCHUNK_ + cc) * 14 + h] - M);
        L += part_ml[(g * NCHUNK_ + cc) * 14 + 7 + h] * e;
        s += part_ctx[(size_t)(g * NCHUNK_ + cc) * (GRP_ * HD_) + h * HD_ + d] * e;
    }
    const int b = g >> 2, kv = g & 3;
    ctx[(size_t)b * D_ + kv * (GRP_ * HD_) + h * HD_ + d] = s / L;
}

// ---------------------------------------------------------------------------
// Final reduce of O-projection split-K partials into d_out.
// ---------------------------------------------------------------------------
__global__ __launch_bounds__(256) void out_finish(const float* __restrict__ P,
                                                  float* __restrict__ out) {
    int t = blockIdx.x * 256 + threadIdx.x;   // < 32*3584
    float s = 0.f;
#pragma unroll
    for (int kc = 0; kc < NKC_; ++kc) s += P[(size_t)kc * (32 * D_) + t];
    out[t] = s;
}

// ---------------------------------------------------------------------------
extern "C" void kernel_launch(void* const* d_in, const int* in_sizes, int n_in,
                              void* d_out, int out_size, void* d_ws, size_t ws_size,
                              hipStream_t stream) {
    const float* x    = (const float*)d_in[0];
    const float* wqkv = (const float*)d_in[1];
    const float* bias = (const float*)d_in[2];
    const float* wo   = (const float*)d_in[3];
    const float* rot  = (const float*)d_in[4];
    const float* ck   = (const float*)d_in[5];
    const float* cv   = (const float*)d_in[6];
    const int*   cur  = (const int*)d_in[7];
    float* out = (float*)d_out;
    float* ws  = (float*)d_ws;

    // workspace layout (floats) — no aliasing, ~40 MB total
    float* partials = ws;                                        // 2,359,296
    float* xqkv     = partials + (size_t)NKC_ * 32 * NQKV_;      //   147,456
    float* pctx     = xqkv + (size_t)B_ * NQKV_;                 // 7,340,032
    float* pml      = pctx + (size_t)B_ * NKV_ * NCHUNK_ * GRP_ * HD_; // 114,688
    float* ctx      = pml  + (size_t)B_ * NKV_ * NCHUNK_ * 14;   //   114,688

    // 1) QKV projection (split-K partials)
    proj_kernel<<<dim3(NQKV_ / 128, NKC_), 256, 0, stream>>>(x, wqkv, partials, NQKV_);
    // 2) bias + RoPE + q-scale
    qkv_finish<<<(B_ * NQKV_ / 2) / 256, 256, 0, stream>>>(partials, bias, rot, xqkv);
    // 3) flash-decode attention over (b, kv, chunk)
    attn_kernel<<<B_ * NKV_ * NCHUNK_, 256, 0, stream>>>(xqkv, ck, cv, cur, pctx, pml);
    // 4) combine chunks — one block per (g, head)
    combine_kernel<<<dim3(B_ * NKV_, GRP_), 128, 0, stream>>>(pctx, pml, ctx);
    // 5) output projection (split-K partials, reuse buffer)
    proj_kernel<<<dim3(D_ / 128, NKC_), 256, 0, stream>>>(ctx, wo, partials, D_);
    // 6) reduce into d_out
    out_finish<<<(B_ * D_) / 256, 256, 0, stream>>>(partials, out);
}